// Round 5
// baseline (118.091 us; speedup 1.0000x reference)
//
#include <hip/hip_runtime.h>
#include <math.h>

#define B_ 8
#define P_ 32
#define S_ 512
#define D_ 64
#define NQS 5    // query splits per bp
#define KC 64    // keys per chunk

typedef __attribute__((ext_vector_type(8))) short short8;
typedef __attribute__((ext_vector_type(4))) float f32x4;

static __device__ inline unsigned short f2bf(float f) {
    unsigned u = __float_as_uint(f);
    unsigned r = (u + 0x7FFFu + ((u >> 16) & 1u)) >> 16;
    return (unsigned short)r;
}
static __device__ inline float bf2f(unsigned short s) {
    return __uint_as_float(((unsigned)s) << 16);
}

// ---------------------------------------------------------------------------
// Kernel 1: t -> min/max norm -> elu scale -> tpe (transposed in LDS) ->
// E16[b,r,k] = bf16(exp(score-2)). Grid (64, B).
// ---------------------------------------------------------------------------
__launch_bounds__(256)
__global__ void k_scoresE2(const float* __restrict__ t, const float* __restrict__ alpha_w,
                           unsigned short* __restrict__ E16) {
    const int b = blockIdx.y;
    const int r0 = blockIdx.x * 8;
    const int tid = threadIdx.x, lane = tid & 63, wave = tid >> 6;

    __shared__ float tpeT[16][S_];
    __shared__ float red[8];

    float v0 = t[b * S_ + tid];
    float v1 = t[b * S_ + tid + 256];
    float mn = fminf(v0, v1), mx = fmaxf(v0, v1);
#pragma unroll
    for (int o = 32; o > 0; o >>= 1) {
        mn = fminf(mn, __shfl_xor(mn, o, 64));
        mx = fmaxf(mx, __shfl_xor(mx, o, 64));
    }
    if (lane == 0) { red[wave] = mn; red[4 + wave] = mx; }
    __syncthreads();
    mn = fminf(fminf(red[0], red[1]), fminf(red[2], red[3]));
    mx = fmaxf(fmaxf(red[4], red[5]), fmaxf(red[6], red[7]));

    float aw = alpha_w[0] * 1000.0f;
    float el = aw > 0.0f ? aw : (__expf(aw) - 1.0f);
    float inv = (el + 1.0f) / (mx - mn);

    const float divs[8] = {1.0f, 0.31622776601683794f, 0.1f, 0.031622776601683791f,
                           0.01f, 0.0031622776601683794f, 0.001f, 0.00031622776601683794f};
    {
        float tn0 = (v0 - mn) * inv;
        float tn1 = (v1 - mn) * inv;
#pragma unroll
        for (int f = 0; f < 8; f++) {
            float a0 = tn0 * divs[f], a1 = tn1 * divs[f];
            tpeT[2 * f][tid]           = 0.5f * __sinf(a0);
            tpeT[2 * f + 1][tid]       = 0.5f * __cosf(a0);
            tpeT[2 * f][tid + 256]     = 0.5f * __sinf(a1);
            tpeT[2 * f + 1][tid + 256] = 0.5f * __cosf(a1);
        }
    }
    __syncthreads();

    const int ra = r0 + wave * 2, rb = ra + 1;
    float qa[16], qb[16];
#pragma unroll
    for (int f = 0; f < 16; f++) { qa[f] = tpeT[f][ra]; qb[f] = tpeT[f][rb]; }

    unsigned* Ea = (unsigned*)(E16 + ((size_t)(b * S_) + ra) * S_);
    unsigned* Eb = (unsigned*)(E16 + ((size_t)(b * S_) + rb) * S_);
#pragma unroll
    for (int j = 0; j < 4; j++) {
        int k0 = j * 128 + lane * 2;
        float a0 = 0.f, a1 = 0.f, b0 = 0.f, b1 = 0.f;
#pragma unroll
        for (int f = 0; f < 16; f++) {
            float2 kv = *(const float2*)&tpeT[f][k0];
            a0 += qa[f] * kv.x; a1 += qa[f] * kv.y;
            b0 += qb[f] * kv.x; b1 += qb[f] * kv.y;
        }
        unsigned ea0 = f2bf(__expf(a0 - 2.0f)), ea1 = f2bf(__expf(a1 - 2.0f));
        unsigned eb0 = f2bf(__expf(b0 - 2.0f)), eb1 = f2bf(__expf(b1 - 2.0f));
        Ea[j * 64 + lane] = ea0 | (ea1 << 16);
        Eb[j * 64 + lane] = eb0 | (eb1 << 16);
    }
}

// ---------------------------------------------------------------------------
// Kernel 2: MFMA attention. Grid 1280 = b + 8*(p + 32*q): all blocks of a
// batch on one XCD (E16+x L2-hot). 256 threads (4 waves), 1 output tile/wave.
// LDS B-operand stored directly in B-fragment order -> conflict-free reads.
// Tile ct=4 carries the mask column: denominator falls out of the MFMA.
// ---------------------------------------------------------------------------
__launch_bounds__(256, 5)
__global__ void k_attn5(const float* __restrict__ x, const float* __restrict__ mask,
                        const unsigned short* __restrict__ E16, float* __restrict__ out) {
    const int bid = blockIdx.x;
    const int b = bid & 7;
    const int rdec = bid >> 3;
    const int p = rdec & 31;
    const int q = rdec >> 5;               // 0..4
    const int bp = b * P_ + p;
    const int tid = threadIdx.x, lane = tid & 63, wave = tid >> 6;
    const int quad = lane >> 4, nlane = lane & 15;
    const int c64 = tid & 63, kg = tid >> 6;   // staging: col, key-group(16)

    __shared__ float maskL[S_];
    __shared__ short kidxL[S_], qidxL[S_];
    __shared__ int cntS[2];
    __shared__ __align__(16) unsigned short Bfrag[2][2][5][520];  // 20.8 KB

    const float* maskBP = mask + (size_t)bp * S_;
    const float* xBP = x + (size_t)bp * S_ * D_;
    float* outBP = out + (size_t)bp * S_ * D_;
    const float4* x4 = (const float4*)xBP;
    float4* out4 = (float4*)outBP;
    const unsigned short* Eb = E16 + (size_t)b * S_ * S_;

    for (int i = tid; i < S_; i += 256) maskL[i] = maskBP[i];
    __syncthreads();

    if (wave == 0) {
        int nk = 0, nq = 0;
        for (int c = 0; c < 8; c++) {
            int tt = c * 64 + lane;
            bool isk = maskL[tt] >= 0.5f;
            unsigned long long bm = __ballot(isk);
            int pb = __popcll(bm & ((1ull << lane) - 1ull));
            if (isk) kidxL[nk + pb] = (short)tt;
            else     qidxL[nq + lane - pb] = (short)tt;
            int c1 = __popcll(bm);
            nk += c1; nq += 64 - c1;
        }
        if (lane == 0) { cntS[0] = nk; cntS[1] = nq; }
    }
    __syncthreads();
    const int NK = cntS[0], NQ = cntS[1];

    // ---- copy phase: this block's fifth of the mask=1 rows ----
    {
        int nk5 = (NK + NQS - 1) / NQS;
        int j0 = q * nk5, j1 = min(NK, j0 + nk5);
        for (int e = j0 * 16 + tid; e < j1 * 16; e += 256) {
            int s = kidxL[e >> 4];
            out4[s * 16 + (e & 15)] = x4[s * 16 + (e & 15)];
        }
    }

    // ---- query phase: this block's fifth of the compacted query list ----
    const int qq = (NQ + NQS - 1) / NQS;
    const int qb0 = q * qq;
    const int rows = min(NQ, qb0 + qq) - qb0;
    if (rows <= 0) return;
    const int NT = (rows + 15) >> 4;
    const bool tw = wave < NT;

    const unsigned short* Arow;
    {
        int rowl = min(wave * 16 + nlane, rows - 1);
        Arow = Eb + (size_t)qidxL[qb0 + rowl] * S_;
    }

    auto loadx = [&](int kcv, float* xr) {
        const float* base = xBP + (size_t)(kcv + kg * 16) * D_ + c64;
#pragma unroll
        for (int i = 0; i < 16; i++) xr[i] = base[i * D_];
    };
    auto stage = [&](int bufi, int kcv, const float* xr) {
        const int kc2 = kg >> 1;
        const int ct = c64 >> 4;
#pragma unroll
        for (int g = 0; g < 2; g++) {
            short8 w;
#pragma unroll
            for (int j = 0; j < 8; j++) {
                int k = kg * 16 + g * 8 + j;
                w[j] = (short)f2bf(xr[g * 8 + j] * maskL[kcv + k]);
            }
            int lanep = ((kg & 1) * 2 + g) * 16 + (c64 & 15);
            *(short8*)&Bfrag[bufi][kc2][ct][lanep * 8] = w;
        }
        if (tid < 128) {   // mask tile (ct=4): col 64 = mask, rest 0
            int kc2m = tid >> 6;
            short8 w;
#pragma unroll
            for (int j = 0; j < 8; j++) {
                int k = kc2m * 32 + ((tid >> 4) & 3) * 8 + j;
                w[j] = ((tid & 15) == 0) ? (short)f2bf(maskL[kcv + k]) : (short)0;
            }
            *(short8*)&Bfrag[bufi][kc2m][4][(tid & 63) * 8] = w;
        }
    };

    f32x4 acc[5];
#pragma unroll
    for (int ct = 0; ct < 5; ct++) acc[ct] = (f32x4){0.f, 0.f, 0.f, 0.f};

    float xr[16], xrn[16];
    loadx(0, xr);
    stage(0, 0, xr);
    short8 a0 = *(const short8*)(Arow + quad * 8);
    short8 a1 = *(const short8*)(Arow + 32 + quad * 8);
    __syncthreads();

    for (int c = 0; c < 8; c++) {
        const int kc = c * KC;
        const int cur = c & 1;
        short8 an0, an1;
        if (c < 7) {
            loadx(kc + KC, xrn);
            an0 = *(const short8*)(Arow + kc + KC + quad * 8);
            an1 = *(const short8*)(Arow + kc + KC + 32 + quad * 8);
        }
#pragma unroll
        for (int ct = 0; ct < 5; ct++) {
            short8 b0 = *(const short8*)&Bfrag[cur][0][ct][lane * 8];
            short8 b1 = *(const short8*)&Bfrag[cur][1][ct][lane * 8];
            if (tw) {
                acc[ct] = __builtin_amdgcn_mfma_f32_16x16x32_bf16(a0, b0, acc[ct], 0, 0, 0);
                acc[ct] = __builtin_amdgcn_mfma_f32_16x16x32_bf16(a1, b1, acc[ct], 0, 0, 0);
            }
        }
        if (c < 7) stage(cur ^ 1, kc + KC, xrn);
        __syncthreads();
        a0 = an0; a1 = an1;
    }

    // ---- epilogue: add self term, normalize, store ----
    if (tw) {
#pragma unroll
        for (int reg = 0; reg < 4; reg++) {
            float den = __shfl(acc[4][reg], lane & 48, 64);  // col 64 value
            int rowl = wave * 16 + quad * 4 + reg;
            if (rowl < rows) {
                int sg = qidxL[qb0 + rowl];
                float ws = bf2f(Eb[(size_t)sg * (S_ + 1)]);
                float inv = 1.0f / (den + ws);
#pragma unroll
                for (int ct = 0; ct < 4; ct++) {
                    int col = ct * 16 + nlane;
                    float xv = xBP[(size_t)sg * D_ + col];
                    outBP[(size_t)sg * D_ + col] = (acc[ct][reg] + ws * xv) * inv;
                }
            }
        }
    }
}

// ---------------------------------------------------------------------------
extern "C" void kernel_launch(void* const* d_in, const int* in_sizes, int n_in,
                              void* d_out, int out_size, void* d_ws, size_t ws_size,
                              hipStream_t stream) {
    const float* t       = (const float*)d_in[0]; // (B,S)
    const float* x       = (const float*)d_in[1]; // (B,P,S,D)
    const float* mask    = (const float*)d_in[2]; // (B,P,S)
    const float* alpha_w = (const float*)d_in[3]; // (1,1)
    float* out = (float*)d_out;

    unsigned short* E16 = (unsigned short*)d_ws;   // B*S*S bf16 = 4 MB

    k_scoresE2<<<dim3(S_ / 8, B_), dim3(256), 0, stream>>>(t, alpha_w, E16);
    k_attn5<<<dim3(B_ * P_ * NQS), dim3(256), 0, stream>>>(x, mask, E16, out);
}